// Round 8
// baseline (121.717 us; speedup 1.0000x reference)
//
#include <hip/hip_runtime.h>

// LIF scan: z [B=32, T=1024, H=512] fp32 -> out [32,1024,512] fp32
//   V_t = 0.9*V_{t-1} + z[:,t-1,:] - (V_{t-1} > 1)      (exact fp32 op order)
//   out[:,t,:] = (V_t > 1) ? 1 : 0,  out[:,0,:] = 0
//
// Evidence ladder:
//   R4 (bid=b*8+s, 4 prod): 42.7 us, 2.36 TB/s.
//   R5 triple-buffer/counted-vmcnt: 48.9 -> prefetch depth NOT the lever.
//   R6 64 fat blocks (12 mem-waves/CU): 35 GB/s/CU but CU-starved.
//   R8 ripple: ~32 active CUs -> per-CU cap again. Streams need 256 CUs.
//   R9 same-XCD sibling decode: ~41 us (~+3%) -> XCD/row locality dead.
// R10 theory: per-CU BW scales with MEMORY-ACTIVE WAVE COUNT
//   (~2.5-3 GB/s per wave under drain-per-phase scheduling):
//   R4/R9 = 5 mem-waves -> 12 GB/s/CU; R6 = 12 -> 35 GB/s/CU.
//   Fix: NPROD 4 -> 8 (one change vs R9). 8 producer streams/CU, each
//   issuing 4 GLDS (16 rows) per phase. Read pole ~35us -> ~18us.
//   Keep R9's bid decode (neutral, prerequisite for the contiguity
//   follow-up if this falsifies).

#define LIF_H 512
#define LIF_T 1024
#define CH 128            // timesteps per superchunk (32 KB per buffer)
#define NCH 8
#define NPROD 8
#define NTHREADS (64 * (1 + NPROD))   // 576

#define GLDS(gptr, lptr)                                                     \
    __builtin_amdgcn_global_load_lds(                                        \
        (const __attribute__((address_space(1))) void*)(gptr),               \
        (__attribute__((address_space(3))) void*)(lptr), 16, 0, 0)

__global__ __launch_bounds__(NTHREADS, 1) void lif_kernel(const float* __restrict__ z,
                                                          float* __restrict__ out) {
    __shared__ float lds[2][CH * 64];

    const int tid  = threadIdx.x;
    const int wave = tid >> 6;
    const int lane = tid & 63;
    const int bid  = blockIdx.x;        // 0..255
    // R9 decode kept: XCD = bid%8 = b%8 -> a batch's 8 siblings colocate.
    const int b    = bid & 31;          // batch
    const int h0   = (bid >> 5) << 6;   // 64-wide h-slice index s = bid>>5

    const float* zb = z   + b * (LIF_T * LIF_H) + h0;   // row t = zb + t*512
    float*       ob = out + b * (LIF_T * LIF_H) + h0;

    // ---- prologue: stage chunk 0; consumer zeroes the t=0 row ----
    if (wave == 0) {
        ob[lane] = 0.0f;
    } else {
        const int p = wave - 1;         // 0..7
#pragma unroll
        for (int j = 0; j < 4; ++j) {
            const int r0 = p * 16 + j * 4;   // each GLDS covers 4 rows
            GLDS(zb + (r0 + (lane >> 4)) * LIF_H + (lane & 15) * 4,
                 &lds[0][r0 * 64]);
        }
        __builtin_amdgcn_sched_barrier(0);
        asm volatile("s_waitcnt vmcnt(0)" ::: "memory");
    }
    __builtin_amdgcn_s_barrier();

    float V = 0.0f;
    float r = 0.0f;                     // reset = previous spike (V0=0 -> 0)

#define LDRB(rb, sub)                                                        \
    _Pragma("unroll")                                                        \
    for (int i = 0; i < 32; ++i) rb[i] = lb[((sub) * 32 + i) * 64 + lane];

#define CHAIN(rb, s0, N)                                                     \
    _Pragma("unroll")                                                        \
    for (int i = 0; i < (N); ++i) {                                          \
        const float u  = __fadd_rn(__fmul_rn(0.9f, V), rb[i]);               \
        const float Vn = __fsub_rn(u, r);                                    \
        const float sp = (Vn > 1.0f) ? 1.0f : 0.0f;                          \
        ob[((s0) + i + 1) * LIF_H + lane] = sp;                              \
        r = sp;                                                              \
        V = Vn;                                                              \
    }

#pragma unroll 1
    for (int c = 0; c < NCH; ++c) {
        if (wave > 0) {
            // ---- producers: stage chunk c+1 into the other buffer ----
            if (c + 1 < NCH) {
                const int p = wave - 1;
                float* dst = lds[(c + 1) & 1];
                const float* src = zb + (c + 1) * CH * LIF_H;
#pragma unroll
                for (int j = 0; j < 4; ++j) {
                    const int r0 = p * 16 + j * 4;
                    GLDS(src + (r0 + (lane >> 4)) * LIF_H + (lane & 15) * 4,
                         &dst[r0 * 64]);
                }
                __builtin_amdgcn_sched_barrier(0);
                asm volatile("s_waitcnt vmcnt(0)" ::: "memory");
            }
        } else {
            // ---- consumer: scan chunk c from LDS (reg double-buffered) ----
            const float* lb = lds[c & 1];
            const int s0 = c * CH;
            float rbA[32], rbB[32];
            LDRB(rbA, 0);
            LDRB(rbB, 1);
            __builtin_amdgcn_sched_barrier(0);
            CHAIN(rbA, s0 + 0, 32);
            LDRB(rbA, 2);
            __builtin_amdgcn_sched_barrier(0);
            CHAIN(rbB, s0 + 32, 32);
            LDRB(rbB, 3);
            __builtin_amdgcn_sched_barrier(0);
            CHAIN(rbA, s0 + 64, 32);
            __builtin_amdgcn_sched_barrier(0);
            if (c < NCH - 1) {
                CHAIN(rbB, s0 + 96, 32);
            } else {
                CHAIN(rbB, s0 + 96, 31);   // steps 992..1022
            }
        }
        __builtin_amdgcn_s_barrier();
    }
}

extern "C" void kernel_launch(void* const* d_in, const int* in_sizes, int n_in,
                              void* d_out, int out_size, void* d_ws, size_t ws_size,
                              hipStream_t stream) {
    const float* z = (const float*)d_in[0];
    float* out = (float*)d_out;
    hipLaunchKernelGGL(lif_kernel, dim3(256), dim3(NTHREADS), 0, stream, z, out);
}

// Round 9
// 112.256 us; speedup vs baseline: 1.0843x; 1.0843x over previous
//
#include <hip/hip_runtime.h>

// LIF scan: z [B=32, T=1024, H=512] fp32 -> out [32,1024,512] fp32
//   V_t = 0.9*V_{t-1} + z[:,t-1,:] - (V_{t-1} > 1)      (exact fp32 op order)
//   out[:,t,:] = (V_t > 1) ? 1 : 0,  out[:,0,:] = 0
//
// Evidence ladder:
//   R4 (4 prod, vmcnt(0)/phase): 42.7 us, 2.36 TB/s.
//   R5 triple-buffer/counted-vmcnt: 48.9 -> prefetch depth NOT the lever.
//   R6 64 fat blocks: 27 GB/s/CU (1KB-contig GLDS) but CU-starved.
//   R7 compact-ws + transpose pass: sum ~57us -> extra pass not worth it.
//   R8 ripple: ~32 active CUs -> per-CU cap. Streams need 256 CUs.
//   R9 same-XCD sibling decode: ~41 us (~+3%) -> XCD/row locality dead.
//   R10 NPROD 4->8: 47-51 us -> mem-wave count NOT the lever (256B islands
//       pin per-CU rate at ~9 GB/s regardless of wave count).
// R11 theory: L2 WRITE POLLUTION. Spike stores (64 MB/iter, full-line,
//   never re-read) churn dirty lines through 32 MB aggregate L2 while the
//   GLDS read stream depends on L2/L3 retention (FETCH 33 MB < 64 MB input
//   = half the reads are cache-absorbed). Mark all spike stores
//   non-temporal (evict-first, stop competing with reads). One change vs
//   R9; reads untouched.

#define LIF_H 512
#define LIF_T 1024
#define CH 128            // timesteps per superchunk (32 KB per buffer)
#define NCH 8
#define NPROD 4
#define NTHREADS (64 * (1 + NPROD))

#define GLDS(gptr, lptr)                                                     \
    __builtin_amdgcn_global_load_lds(                                        \
        (const __attribute__((address_space(1))) void*)(gptr),               \
        (__attribute__((address_space(3))) void*)(lptr), 16, 0, 0)

__global__ __launch_bounds__(NTHREADS, 1) void lif_kernel(const float* __restrict__ z,
                                                          float* __restrict__ out) {
    __shared__ float lds[2][CH * 64];

    const int tid  = threadIdx.x;
    const int wave = tid >> 6;
    const int lane = tid & 63;
    const int bid  = blockIdx.x;        // 0..255
    // R9 decode kept (measured >= R4): XCD = bid%8 = b%8, siblings colocate.
    const int b    = bid & 31;          // batch
    const int h0   = (bid >> 5) << 6;   // 64-wide h-slice index s = bid>>5

    const float* zb = z   + b * (LIF_T * LIF_H) + h0;   // row t = zb + t*512
    float*       ob = out + b * (LIF_T * LIF_H) + h0;

    // ---- prologue: stage chunk 0; consumer zeroes the t=0 row ----
    if (wave == 0) {
        __builtin_nontemporal_store(0.0f, &ob[lane]);
    } else {
        const int p = wave - 1;         // 0..3
#pragma unroll
        for (int j = 0; j < 8; ++j) {
            const int r0 = p * 32 + j * 4;
            GLDS(zb + (r0 + (lane >> 4)) * LIF_H + (lane & 15) * 4,
                 &lds[0][r0 * 64]);
        }
        __builtin_amdgcn_sched_barrier(0);
        asm volatile("s_waitcnt vmcnt(0)" ::: "memory");
    }
    __builtin_amdgcn_s_barrier();

    float V = 0.0f;
    float r = 0.0f;                     // reset = previous spike (V0=0 -> 0)

#define LDRB(rb, sub)                                                        \
    _Pragma("unroll")                                                        \
    for (int i = 0; i < 32; ++i) rb[i] = lb[((sub) * 32 + i) * 64 + lane];

#define CHAIN(rb, s0, N)                                                     \
    _Pragma("unroll")                                                        \
    for (int i = 0; i < (N); ++i) {                                          \
        const float u  = __fadd_rn(__fmul_rn(0.9f, V), rb[i]);               \
        const float Vn = __fsub_rn(u, r);                                    \
        const float sp = (Vn > 1.0f) ? 1.0f : 0.0f;                          \
        __builtin_nontemporal_store(sp, &ob[((s0) + i + 1) * LIF_H + lane]); \
        r = sp;                                                              \
        V = Vn;                                                              \
    }

#pragma unroll 1
    for (int c = 0; c < NCH; ++c) {
        if (wave > 0) {
            // ---- producers: stage chunk c+1 into the other buffer ----
            if (c + 1 < NCH) {
                const int p = wave - 1;
                float* dst = lds[(c + 1) & 1];
                const float* src = zb + (c + 1) * CH * LIF_H;
#pragma unroll
                for (int j = 0; j < 8; ++j) {
                    const int r0 = p * 32 + j * 4;
                    GLDS(src + (r0 + (lane >> 4)) * LIF_H + (lane & 15) * 4,
                         &dst[r0 * 64]);
                }
                __builtin_amdgcn_sched_barrier(0);
                asm volatile("s_waitcnt vmcnt(0)" ::: "memory");
            }
        } else {
            // ---- consumer: scan chunk c from LDS (reg double-buffered) ----
            const float* lb = lds[c & 1];
            const int s0 = c * CH;
            float rbA[32], rbB[32];
            LDRB(rbA, 0);
            LDRB(rbB, 1);
            __builtin_amdgcn_sched_barrier(0);
            CHAIN(rbA, s0 + 0, 32);
            LDRB(rbA, 2);
            __builtin_amdgcn_sched_barrier(0);
            CHAIN(rbB, s0 + 32, 32);
            LDRB(rbB, 3);
            __builtin_amdgcn_sched_barrier(0);
            CHAIN(rbA, s0 + 64, 32);
            __builtin_amdgcn_sched_barrier(0);
            if (c < NCH - 1) {
                CHAIN(rbB, s0 + 96, 32);
            } else {
                CHAIN(rbB, s0 + 96, 31);   // steps 992..1022
            }
        }
        __builtin_amdgcn_s_barrier();
    }
}

extern "C" void kernel_launch(void* const* d_in, const int* in_sizes, int n_in,
                              void* d_out, int out_size, void* d_ws, size_t ws_size,
                              hipStream_t stream) {
    const float* z = (const float*)d_in[0];
    float* out = (float*)d_out;
    hipLaunchKernelGGL(lif_kernel, dim3(256), dim3(NTHREADS), 0, stream, z, out);
}